// Round 2
// baseline (576.505 us; speedup 1.0000x reference)
//
#include <hip/hip_runtime.h>
#include <cstdint>
#include <cstddef>

// Problem constants (fixed by the reference file)
#define NB   8
#define VV   4096
#define KNN  40
#define NTOT 32768
#define CAP  512   // compact within-radius list capacity per query

// ---------------------------------------------------------------------------
// Kernel 1: coords = x@W_sp + b_sp ; feat = x@W_prop + b_prop ;
//           xW = x @ W_out[128:192,:]  (written into d_out, fused later)
// ---------------------------------------------------------------------------
__global__ __launch_bounds__(256) void k_prep(
    const float* __restrict__ x, const float* __restrict__ W_prop,
    const float* __restrict__ b_prop, const float* __restrict__ W_sp,
    const float* __restrict__ b_sp, const float* __restrict__ W_out,
    float* __restrict__ coords, float* __restrict__ feat,
    float* __restrict__ xW)
{
  __shared__ float xt[64][65];
  const int t = threadIdx.x;
  const int row0 = blockIdx.x * 64;

  #pragma unroll
  for (int i = 0; i < 16; ++i) {
    int idx = t + i * 256;
    xt[idx >> 6][idx & 63] = x[(size_t)row0 * 64 + idx];
  }
  __syncthreads();

  // feat: 64 cols, 4 row-groups of 16
  {
    const int col = t & 63, rb = (t >> 6) * 16;
    float acc[16];
    #pragma unroll
    for (int i = 0; i < 16; ++i) acc[i] = b_prop[col];
    for (int k = 0; k < 64; ++k) {
      const float w = W_prop[k * 64 + col];
      #pragma unroll
      for (int i = 0; i < 16; ++i) acc[i] += xt[rb + i][k] * w;
    }
    #pragma unroll
    for (int i = 0; i < 16; ++i)
      feat[(size_t)(row0 + rb + i) * 64 + col] = acc[i];
  }

  // xW = x @ W_out[128:192,:]  (no bias here; b_out added in k_out)
  {
    const int col = t & 127, who = t >> 7;
    #pragma unroll
    for (int p = 0; p < 2; ++p) {
      const int rb = who * 16 + p * 32;
      float acc[16];
      #pragma unroll
      for (int i = 0; i < 16; ++i) acc[i] = 0.f;
      for (int k = 0; k < 64; ++k) {
        const float w = W_out[(size_t)(128 + k) * 128 + col];
        #pragma unroll
        for (int i = 0; i < 16; ++i) acc[i] += xt[rb + i][k] * w;
      }
      #pragma unroll
      for (int i = 0; i < 16; ++i)
        xW[(size_t)(row0 + rb + i) * 128 + col] = acc[i];
    }
  }

  // coords: one row per thread (t<64)
  if (t < 64) {
    float a0 = b_sp[0], a1 = b_sp[1], a2 = b_sp[2], a3 = b_sp[3];
    for (int k = 0; k < 64; ++k) {
      const float xv = xt[t][k];
      a0 += xv * W_sp[k * 4 + 0];
      a1 += xv * W_sp[k * 4 + 1];
      a2 += xv * W_sp[k * 4 + 2];
      a3 += xv * W_sp[k * 4 + 3];
    }
    ((float4*)coords)[row0 + t] = make_float4(a0, a1, a2, a3);
  }
}

// ---------------------------------------------------------------------------
// Kernel 2: per-query KNN (radius-filter + rank-40 threshold) + weighted
// max/mean aggregation. One wave per query; lane = feature dim for agg.
// ---------------------------------------------------------------------------
template <int NJ>
__device__ __forceinline__ float bsearch_tau(const unsigned* dv) {
  // smallest bit pattern 'hi' with count(dsq_bits <= hi) >= KNN.
  unsigned lo = 0, hi = 0x3F800000u;  // bits(1.0f); all values <= 1.0
  while (lo < hi) {
    const unsigned mid = (lo + hi) >> 1;
    int cnt = 0;
    #pragma unroll
    for (int j = 0; j < NJ; ++j) cnt += (dv[j] <= mid) ? 1 : 0;
    #pragma unroll
    for (int off = 32; off; off >>= 1) cnt += __shfl_xor(cnt, off);
    if (cnt >= KNN) hi = mid; else lo = mid + 1;
  }
  return __uint_as_float(hi);
}

__global__ __launch_bounds__(256, 2) void k_knn(
    const float* __restrict__ coords, const float* __restrict__ feat,
    float* __restrict__ agg)
{
  __shared__ float4 cs[VV];            // 64 KB: event coords (AoS)
  __shared__ uint2 lists[4][CAP];      // 16 KB: per-wave compact lists

  const int t = threadIdx.x, lane = t & 63, wv = t >> 6;
  const int bid = blockIdx.x;
  const int ev = bid >> 7;             // 128 blocks per event
  const int qbase = (bid & 127) * 32;  // 32 queries per block
  const int evbase = ev * VV;

  {
    const float4* cg = (const float4*)coords + evbase;
    for (int i = t; i < VV; i += 256) cs[i] = cg[i];
  }
  __syncthreads();

  uint2* list = lists[wv];
  const float* fe = feat + (size_t)evbase * 64;

  for (int qi = 0; qi < 8; ++qi) {
    const int q = qbase + wv * 8 + qi;   // local vertex id in event
    const float4 qc = cs[q];
    int M = 0;

    // Pass 1: radius filter + stream compaction into LDS list
    for (int base = 0; base < VV; base += 64) {
      const int c = base + lane;
      const float4 cc = cs[c];
      const float dx = qc.x - cc.x, dy = qc.y - cc.y;
      const float dz = qc.z - cc.z, dw = qc.w - cc.w;
      const float dsq = dx * dx + dy * dy + dz * dz + dw * dw;
      const bool pred = (dsq <= 1.0f) && (c != q);
      const unsigned long long bm = __ballot(pred);
      if (pred) {
        const int pos = M + (int)__popcll(bm & ((1ull << lane) - 1ull));
        if (pos < CAP)
          list[pos] = make_uint2(__float_as_uint(dsq), (unsigned)c);
      }
      M += (int)__popcll(bm);
    }

    float tau = 1.0f;
    int selfcnt = 0;
    float vmax = -__builtin_inff(), vsum = 0.f;

    if (M <= CAP) {
      if (M > KNN) {
        unsigned dv[8];
        #pragma unroll
        for (int j = 0; j < 8; ++j) {
          const int e = lane + j * 64;
          dv[j] = (e < M) ? list[e].x : 0x7F800000u;  // INF pad
        }
        if (M <= 128) tau = bsearch_tau<2>(dv);
        else          tau = bsearch_tau<8>(dv);
      } else {
        selfcnt = KNN - M;   // out-of-radius slots -> self, w = 1
      }
      // Aggregate selected neighbors (lane = feature dim)
      for (int e = 0; e < M; ++e) {
        const uint2 en = list[e];                 // uniform broadcast read
        const float d = __uint_as_float(en.x);
        if (d <= tau) {
          const float w = __expf(-10.f * d);
          const float v = fe[(size_t)en.y * 64 + lane] * w;
          vmax = fmaxf(vmax, v);
          vsum += v;
        }
      }
    } else {
      // Exact fallback (list overflow — statistically unreachable)
      unsigned lo = 0, hi = 0x3F800000u;
      while (lo < hi) {
        const unsigned mid = (lo + hi) >> 1;
        const float fm = __uint_as_float(mid);
        int cnt = 0;
        for (int base = 0; base < VV; base += 64) {
          const int c = base + lane;
          const float4 cc = cs[c];
          const float dx = qc.x - cc.x, dy = qc.y - cc.y;
          const float dz = qc.z - cc.z, dw = qc.w - cc.w;
          const float dsq = dx * dx + dy * dy + dz * dz + dw * dw;
          cnt += (dsq <= fm && c != q) ? 1 : 0;
        }
        #pragma unroll
        for (int off = 32; off; off >>= 1) cnt += __shfl_xor(cnt, off);
        if (cnt >= KNN) hi = mid; else lo = mid + 1;
      }
      tau = __uint_as_float(hi);
      for (int c = 0; c < VV; ++c) {
        if (c == q) continue;
        const float4 cc = cs[c];
        const float dx = qc.x - cc.x, dy = qc.y - cc.y;
        const float dz = qc.z - cc.z, dw = qc.w - cc.w;
        const float dsq = dx * dx + dy * dy + dz * dz + dw * dw;
        if (dsq <= tau) {
          const float w = __expf(-10.f * dsq);
          const float v = fe[(size_t)c * 64 + lane] * w;
          vmax = fmaxf(vmax, v);
          vsum += v;
        }
      }
    }

    const float fs = fe[(size_t)q * 64 + lane];
    if (selfcnt > 0) {
      vmax = fmaxf(vmax, fs);
      vsum += (float)selfcnt * fs;
    }

    const int g = evbase + q;
    agg[(size_t)g * 128 + lane]      = vmax;
    agg[(size_t)g * 128 + 64 + lane] = vsum * (1.f / 40.f);
  }
}

// ---------------------------------------------------------------------------
// Kernel 3: out = tanh(agg @ W_out[0:128,:] + xW + b_out), in place on d_out
// ---------------------------------------------------------------------------
__global__ __launch_bounds__(256) void k_out(
    const float* __restrict__ agg, const float* __restrict__ W_out,
    const float* __restrict__ b_out, float* __restrict__ out)
{
  __shared__ float at[64][129];
  const int t = threadIdx.x;
  const int row0 = blockIdx.x * 64;

  #pragma unroll
  for (int i = 0; i < 32; ++i) {
    int idx = t + i * 256;
    at[idx >> 7][idx & 127] = agg[(size_t)row0 * 128 + idx];
  }
  __syncthreads();

  const int col = t & 127, who = t >> 7;
  #pragma unroll
  for (int p = 0; p < 2; ++p) {
    const int rb = who * 16 + p * 32;
    float acc[16];
    #pragma unroll
    for (int i = 0; i < 16; ++i) acc[i] = 0.f;
    for (int k = 0; k < 128; ++k) {
      const float w = W_out[(size_t)k * 128 + col];
      #pragma unroll
      for (int i = 0; i < 16; ++i) acc[i] += at[rb + i][k] * w;
    }
    const float bb = b_out[col];
    #pragma unroll
    for (int i = 0; i < 16; ++i) {
      const size_t o = (size_t)(row0 + rb + i) * 128 + col;
      float v = acc[i] + bb + out[o];   // out currently holds xW
      v = fminf(15.f, fmaxf(-15.f, v)); // tanh(|15|) == 1 in fp32
      const float e = __expf(2.f * v);
      out[o] = (e - 1.f) / (e + 1.f);
    }
  }
}

// ---------------------------------------------------------------------------
extern "C" void kernel_launch(void* const* d_in, const int* in_sizes, int n_in,
                              void* d_out, int out_size, void* d_ws, size_t ws_size,
                              hipStream_t stream) {
  const float* x      = (const float*)d_in[0];
  const float* W_prop = (const float*)d_in[1];
  const float* b_prop = (const float*)d_in[2];
  const float* W_sp   = (const float*)d_in[3];
  const float* b_sp   = (const float*)d_in[4];
  const float* W_out  = (const float*)d_in[5];
  const float* b_out  = (const float*)d_in[6];
  // d_in[7] = row_splits (regular, constants hard-coded)

  float* out = (float*)d_out;
  char* ws = (char*)d_ws;
  float* coords = (float*)ws;                                  // 512 KB
  float* feat   = (float*)(ws + (512 << 10));                  // 8 MB
  float* agg    = (float*)(ws + (512 << 10) + (8 << 20));      // 16 MB
  // total ws use: ~24.5 MB

  k_prep<<<NTOT / 64, 256, 0, stream>>>(x, W_prop, b_prop, W_sp, b_sp, W_out,
                                        coords, feat, out /* xW staged here */);
  k_knn<<<NB * (VV / 32), 256, 0, stream>>>(coords, feat, agg);
  k_out<<<NTOT / 64, 256, 0, stream>>>(agg, W_out, b_out, out);
}

// Round 3
// 277.506 us; speedup vs baseline: 2.0775x; 2.0775x over previous
//
#include <hip/hip_runtime.h>
#include <cstdint>
#include <cstddef>

// Problem constants (fixed by the reference file)
#define NB   8
#define VV   4096
#define KNN  40
#define NTOT 32768
#define CAP  512   // compact within-radius list capacity per query

// ---------------------------------------------------------------------------
// Kernel 1: coords = x@W_sp + b_sp ; feat = x@W_prop + b_prop ;
//           xW = x @ W_out[128:192,:]  (written into d_out, fused later)
// ---------------------------------------------------------------------------
__global__ __launch_bounds__(256) void k_prep(
    const float* __restrict__ x, const float* __restrict__ W_prop,
    const float* __restrict__ b_prop, const float* __restrict__ W_sp,
    const float* __restrict__ b_sp, const float* __restrict__ W_out,
    float* __restrict__ coords, float* __restrict__ feat,
    float* __restrict__ xW)
{
  __shared__ float xt[64][64];   // reads are broadcast -> no pad needed
  const int t = threadIdx.x;
  const int row0 = blockIdx.x * 64;

  #pragma unroll
  for (int i = 0; i < 16; ++i) {
    int idx = t + i * 256;
    xt[idx >> 6][idx & 63] = x[(size_t)row0 * 64 + idx];
  }
  __syncthreads();

  // feat: 64 cols, 4 row-groups of 16
  {
    const int col = t & 63, rb = (t >> 6) * 16;
    float acc[16];
    #pragma unroll
    for (int i = 0; i < 16; ++i) acc[i] = b_prop[col];
    for (int k = 0; k < 64; k += 4) {
      const float w0 = W_prop[(k + 0) * 64 + col];
      const float w1 = W_prop[(k + 1) * 64 + col];
      const float w2 = W_prop[(k + 2) * 64 + col];
      const float w3 = W_prop[(k + 3) * 64 + col];
      #pragma unroll
      for (int i = 0; i < 16; ++i) {
        const float4 a4 = *(const float4*)&xt[rb + i][k];
        acc[i] += a4.x * w0 + a4.y * w1 + a4.z * w2 + a4.w * w3;
      }
    }
    #pragma unroll
    for (int i = 0; i < 16; ++i)
      feat[(size_t)(row0 + rb + i) * 64 + col] = acc[i];
  }

  // xW = x @ W_out[128:192,:]  (no bias here; b_out added in k_out)
  {
    const int col = t & 127, who = t >> 7;
    #pragma unroll
    for (int p = 0; p < 2; ++p) {
      const int rb = who * 16 + p * 32;
      float acc[16];
      #pragma unroll
      for (int i = 0; i < 16; ++i) acc[i] = 0.f;
      for (int k = 0; k < 64; k += 4) {
        const float w0 = W_out[(size_t)(128 + k + 0) * 128 + col];
        const float w1 = W_out[(size_t)(128 + k + 1) * 128 + col];
        const float w2 = W_out[(size_t)(128 + k + 2) * 128 + col];
        const float w3 = W_out[(size_t)(128 + k + 3) * 128 + col];
        #pragma unroll
        for (int i = 0; i < 16; ++i) {
          const float4 a4 = *(const float4*)&xt[rb + i][k];
          acc[i] += a4.x * w0 + a4.y * w1 + a4.z * w2 + a4.w * w3;
        }
      }
      #pragma unroll
      for (int i = 0; i < 16; ++i)
        xW[(size_t)(row0 + rb + i) * 128 + col] = acc[i];
    }
  }

  // coords: one row per thread (t<64)
  if (t < 64) {
    float a0 = b_sp[0], a1 = b_sp[1], a2 = b_sp[2], a3 = b_sp[3];
    for (int k = 0; k < 64; ++k) {
      const float xv = xt[t][k];
      a0 += xv * W_sp[k * 4 + 0];
      a1 += xv * W_sp[k * 4 + 1];
      a2 += xv * W_sp[k * 4 + 2];
      a3 += xv * W_sp[k * 4 + 3];
    }
    ((float4*)coords)[row0 + t] = make_float4(a0, a1, a2, a3);
  }
}

// ---------------------------------------------------------------------------
// Kernel 2: per-query KNN (radius-filter + rank-40 threshold) + weighted
// max/mean aggregation. One wave per query; lane = feature dim for agg.
// ---------------------------------------------------------------------------
template <int NJ>
__device__ __forceinline__ unsigned bsearch_tau_bits(const unsigned* dv) {
  // smallest bit pattern 'hi' with count(dsq_bits <= hi) >= KNN.
  // Ballot-based count: no cross-lane shuffle chain, scalar-pipe friendly.
  unsigned lo = 0, hi = 0x3F800000u;  // bits(1.0f); all values <= 1.0
  while (lo < hi) {
    const unsigned mid = (lo + hi) >> 1;
    int cnt = 0;
    #pragma unroll
    for (int j = 0; j < NJ; ++j)
      cnt += (int)__popcll(__ballot(dv[j] <= mid));
    if (cnt >= KNN) hi = mid; else lo = mid + 1;
  }
  return hi;
}

__global__ __launch_bounds__(256, 2) void k_knn(
    const float* __restrict__ coords, const float* __restrict__ feat,
    float* __restrict__ agg)
{
  __shared__ float4 cs[VV];            // 64 KB: event coords (AoS)
  __shared__ uint2 lists[4][CAP];      // 16 KB: per-wave compact lists

  const int t = threadIdx.x, lane = t & 63, wv = t >> 6;
  const int bid = blockIdx.x;
  const int ev = bid >> 7;             // 128 blocks per event
  const int qbase = (bid & 127) * 32;  // 32 queries per block
  const int evbase = ev * VV;

  {
    const float4* cg = (const float4*)coords + evbase;
    for (int i = t; i < VV; i += 256) cs[i] = cg[i];
  }
  __syncthreads();

  uint2* list = lists[wv];
  const float* fe = feat + (size_t)evbase * 64;
  const unsigned long long lmask = (1ull << lane) - 1ull;

  for (int qi = 0; qi < 8; ++qi) {
    const int q = qbase + wv * 8 + qi;   // local vertex id in event
    const float4 qc = cs[q];
    int M = 0;

    // Pass 1: radius filter + stream compaction into LDS list
    for (int base = 0; base < VV; base += 64) {
      const int c = base + lane;
      const float4 cc = cs[c];
      const float dx = qc.x - cc.x, dy = qc.y - cc.y;
      const float dz = qc.z - cc.z, dw = qc.w - cc.w;
      const float dsq = dx * dx + dy * dy + dz * dz + dw * dw;
      const bool pred = (dsq <= 1.0f) && (c != q);
      const unsigned long long bm = __ballot(pred);
      if (pred) {
        const int pos = M + (int)__popcll(bm & lmask);
        if (pos < CAP)
          list[pos] = make_uint2(__float_as_uint(dsq), (unsigned)c);
      }
      M += (int)__popcll(bm);
    }

    int selfcnt = 0;
    int Msel = M;
    float vmax = -__builtin_inff(), vsum = 0.f;

    if (M <= CAP) {
      if (M > KNN) {
        // tau = 40th-smallest dsq (bit-pattern binary search, ballot count)
        unsigned taub;
        if (M <= 128) {
          unsigned dv[2];
          #pragma unroll
          for (int j = 0; j < 2; ++j) {
            const int e = lane + j * 64;
            dv[j] = (e < M) ? list[e].x : 0x7F800000u;
          }
          taub = bsearch_tau_bits<2>(dv);
        } else if (M <= 256) {
          unsigned dv[4];
          #pragma unroll
          for (int j = 0; j < 4; ++j) {
            const int e = lane + j * 64;
            dv[j] = (e < M) ? list[e].x : 0x7F800000u;
          }
          taub = bsearch_tau_bits<4>(dv);
        } else {
          unsigned dv[8];
          #pragma unroll
          for (int j = 0; j < 8; ++j) {
            const int e = lane + j * 64;
            dv[j] = (e < M) ? list[e].x : 0x7F800000u;
          }
          taub = bsearch_tau_bits<8>(dv);
        }
        // Re-compact: keep only entries with bits <= taub (the selected ~40).
        // In-place is safe: all 64 lanes' reads (into regs, consumed by the
        // ballot) complete before the write instruction issues, and write
        // positions never exceed the current chunk's end.
        int S = 0;
        for (int be = 0; be < M; be += 64) {
          const int e = be + lane;
          uint2 en = make_uint2(0u, 0u);
          bool p = false;
          if (e < M) { en = list[e]; p = (en.x <= taub); }
          const unsigned long long bm = __ballot(p);
          if (p) list[S + (int)__popcll(bm & lmask)] = en;
          S += (int)__popcll(bm);
        }
        Msel = S;
      } else {
        selfcnt = KNN - M;   // out-of-radius slots -> self, w = 1
      }
      // Aggregate selected neighbors (lane = feature dim); all entries
      // in list[0..Msel) are selected -> branchless body, unrolled for MLP.
      #pragma unroll 4
      for (int e = 0; e < Msel; ++e) {
        const uint2 en = list[e];                 // uniform broadcast read
        const float w = __expf(-10.f * __uint_as_float(en.x));
        const float v = fe[(size_t)en.y * 64 + lane] * w;
        vmax = fmaxf(vmax, v);
        vsum += v;
      }
    } else {
      // Exact fallback (list overflow — statistically unreachable)
      unsigned lo = 0, hi = 0x3F800000u;
      while (lo < hi) {
        const unsigned mid = (lo + hi) >> 1;
        const float fm = __uint_as_float(mid);
        int cnt = 0;
        for (int base = 0; base < VV; base += 64) {
          const int c = base + lane;
          const float4 cc = cs[c];
          const float dx = qc.x - cc.x, dy = qc.y - cc.y;
          const float dz = qc.z - cc.z, dw = qc.w - cc.w;
          const float dsq = dx * dx + dy * dy + dz * dz + dw * dw;
          cnt += (int)__popcll(__ballot(dsq <= fm && c != q));
        }
        if (cnt >= KNN) hi = mid; else lo = mid + 1;
      }
      const float tau = __uint_as_float(hi);
      for (int c = 0; c < VV; ++c) {
        if (c == q) continue;
        const float4 cc = cs[c];
        const float dx = qc.x - cc.x, dy = qc.y - cc.y;
        const float dz = qc.z - cc.z, dw = qc.w - cc.w;
        const float dsq = dx * dx + dy * dy + dz * dz + dw * dw;
        if (dsq <= tau) {
          const float w = __expf(-10.f * dsq);
          const float v = fe[(size_t)c * 64 + lane] * w;
          vmax = fmaxf(vmax, v);
          vsum += v;
        }
      }
    }

    const float fs = fe[(size_t)q * 64 + lane];
    if (selfcnt > 0) {
      vmax = fmaxf(vmax, fs);
      vsum += (float)selfcnt * fs;
    }

    const int g = evbase + q;
    agg[(size_t)g * 128 + lane]      = vmax;
    agg[(size_t)g * 128 + 64 + lane] = vsum * (1.f / 40.f);
  }
}

// ---------------------------------------------------------------------------
// Kernel 3: out = tanh(agg @ W_out[0:128,:] + xW + b_out), in place on d_out
// ---------------------------------------------------------------------------
__global__ __launch_bounds__(256) void k_out(
    const float* __restrict__ agg, const float* __restrict__ W_out,
    const float* __restrict__ b_out, float* __restrict__ out)
{
  __shared__ float at[64][128];  // reads are broadcast -> no pad; 16B aligned
  const int t = threadIdx.x;
  const int row0 = blockIdx.x * 64;

  #pragma unroll
  for (int i = 0; i < 32; ++i) {
    int idx = t + i * 256;
    at[idx >> 7][idx & 127] = agg[(size_t)row0 * 128 + idx];
  }
  __syncthreads();

  const int col = t & 127, who = t >> 7;
  #pragma unroll
  for (int p = 0; p < 2; ++p) {
    const int rb = who * 16 + p * 32;
    float acc[16];
    #pragma unroll
    for (int i = 0; i < 16; ++i) acc[i] = 0.f;
    for (int k = 0; k < 128; k += 4) {
      const float w0 = W_out[(size_t)(k + 0) * 128 + col];
      const float w1 = W_out[(size_t)(k + 1) * 128 + col];
      const float w2 = W_out[(size_t)(k + 2) * 128 + col];
      const float w3 = W_out[(size_t)(k + 3) * 128 + col];
      #pragma unroll
      for (int i = 0; i < 16; ++i) {
        const float4 a4 = *(const float4*)&at[rb + i][k];
        acc[i] += a4.x * w0 + a4.y * w1 + a4.z * w2 + a4.w * w3;
      }
    }
    const float bb = b_out[col];
    #pragma unroll
    for (int i = 0; i < 16; ++i) {
      const size_t o = (size_t)(row0 + rb + i) * 128 + col;
      float v = acc[i] + bb + out[o];   // out currently holds xW
      v = fminf(15.f, fmaxf(-15.f, v)); // tanh(|15|) == 1 in fp32
      const float e = __expf(2.f * v);
      out[o] = (e - 1.f) / (e + 1.f);
    }
  }
}

// ---------------------------------------------------------------------------
extern "C" void kernel_launch(void* const* d_in, const int* in_sizes, int n_in,
                              void* d_out, int out_size, void* d_ws, size_t ws_size,
                              hipStream_t stream) {
  const float* x      = (const float*)d_in[0];
  const float* W_prop = (const float*)d_in[1];
  const float* b_prop = (const float*)d_in[2];
  const float* W_sp   = (const float*)d_in[3];
  const float* b_sp   = (const float*)d_in[4];
  const float* W_out  = (const float*)d_in[5];
  const float* b_out  = (const float*)d_in[6];
  // d_in[7] = row_splits (regular, constants hard-coded)

  float* out = (float*)d_out;
  char* ws = (char*)d_ws;
  float* coords = (float*)ws;                                  // 512 KB
  float* feat   = (float*)(ws + (512 << 10));                  // 8 MB
  float* agg    = (float*)(ws + (512 << 10) + (8 << 20));      // 16 MB
  // total ws use: ~24.5 MB

  k_prep<<<NTOT / 64, 256, 0, stream>>>(x, W_prop, b_prop, W_sp, b_sp, W_out,
                                        coords, feat, out /* xW staged here */);
  k_knn<<<NB * (VV / 32), 256, 0, stream>>>(coords, feat, agg);
  k_out<<<NTOT / 64, 256, 0, stream>>>(agg, W_out, b_out, out);
}

// Round 6
// 233.950 us; speedup vs baseline: 2.4642x; 1.1862x over previous
//
#include <hip/hip_runtime.h>
#include <cstdint>
#include <cstddef>

// Problem constants (fixed by the reference file)
#define NB   8
#define VV   4096
#define KNN  40
#define NTOT 32768
#define CAP  256   // compact within-radius list capacity per query
#define INFB 0x7F800000u
#define ONEB 0x3F800000u

// ---------------------------------------------------------------------------
// Kernel 1: coords = x@W_sp + b_sp ; feat = x@W_prop + b_prop ;
//           xW = x @ W_out[128:192,:]  (written into d_out, fused later)
// ---------------------------------------------------------------------------
__global__ __launch_bounds__(256) void k_prep(
    const float* __restrict__ x, const float* __restrict__ W_prop,
    const float* __restrict__ b_prop, const float* __restrict__ W_sp,
    const float* __restrict__ b_sp, const float* __restrict__ W_out,
    float* __restrict__ coords, float* __restrict__ feat,
    float* __restrict__ xW)
{
  __shared__ float xt[64][64];   // reads are broadcast -> no pad needed
  const int t = threadIdx.x;
  const int row0 = blockIdx.x * 64;

  #pragma unroll
  for (int i = 0; i < 16; ++i) {
    int idx = t + i * 256;
    xt[idx >> 6][idx & 63] = x[(size_t)row0 * 64 + idx];
  }
  __syncthreads();

  // feat: 64 cols, 4 row-groups of 16
  {
    const int col = t & 63, rb = (t >> 6) * 16;
    float acc[16];
    #pragma unroll
    for (int i = 0; i < 16; ++i) acc[i] = b_prop[col];
    for (int k = 0; k < 64; k += 4) {
      const float w0 = W_prop[(k + 0) * 64 + col];
      const float w1 = W_prop[(k + 1) * 64 + col];
      const float w2 = W_prop[(k + 2) * 64 + col];
      const float w3 = W_prop[(k + 3) * 64 + col];
      #pragma unroll
      for (int i = 0; i < 16; ++i) {
        const float4 a4 = *(const float4*)&xt[rb + i][k];
        acc[i] += a4.x * w0 + a4.y * w1 + a4.z * w2 + a4.w * w3;
      }
    }
    #pragma unroll
    for (int i = 0; i < 16; ++i)
      feat[(size_t)(row0 + rb + i) * 64 + col] = acc[i];
  }

  // xW = x @ W_out[128:192,:]  (no bias here; b_out added in k_out)
  {
    const int col = t & 127, who = t >> 7;
    #pragma unroll
    for (int p = 0; p < 2; ++p) {
      const int rb = who * 16 + p * 32;
      float acc[16];
      #pragma unroll
      for (int i = 0; i < 16; ++i) acc[i] = 0.f;
      for (int k = 0; k < 64; k += 4) {
        const float w0 = W_out[(size_t)(128 + k + 0) * 128 + col];
        const float w1 = W_out[(size_t)(128 + k + 1) * 128 + col];
        const float w2 = W_out[(size_t)(128 + k + 2) * 128 + col];
        const float w3 = W_out[(size_t)(128 + k + 3) * 128 + col];
        #pragma unroll
        for (int i = 0; i < 16; ++i) {
          const float4 a4 = *(const float4*)&xt[rb + i][k];
          acc[i] += a4.x * w0 + a4.y * w1 + a4.z * w2 + a4.w * w3;
        }
      }
      #pragma unroll
      for (int i = 0; i < 16; ++i)
        xW[(size_t)(row0 + rb + i) * 128 + col] = acc[i];
    }
  }

  // coords: one row per thread (t<64)
  if (t < 64) {
    float a0 = b_sp[0], a1 = b_sp[1], a2 = b_sp[2], a3 = b_sp[3];
    for (int k = 0; k < 64; ++k) {
      const float xv = xt[t][k];
      a0 += xv * W_sp[k * 4 + 0];
      a1 += xv * W_sp[k * 4 + 1];
      a2 += xv * W_sp[k * 4 + 2];
      a3 += xv * W_sp[k * 4 + 3];
    }
    ((float4*)coords)[row0 + t] = make_float4(a0, a1, a2, a3);
  }
}

// ---------------------------------------------------------------------------
// Kernel 2: per-query KNN + weighted max/mean aggregation.
// 512 threads (8 waves) per block, 8 queries per wave, 2 blocks/CU resident
// (80 KB LDS) -> 4 waves/SIMD for latency hiding.
// ---------------------------------------------------------------------------
template <int NC>
__device__ __forceinline__ unsigned bs40(const uint2* __restrict__ list,
                                         int M, int lane) {
  // smallest bit pattern 'hi' with count(dsq_bits <= hi) >= KNN
  unsigned dv[NC];
  #pragma unroll
  for (int j = 0; j < NC; ++j) {
    const int e = lane + j * 64;
    dv[j] = (e < M) ? list[e].x : INFB;
  }
  unsigned lo = 0, hi = ONEB;
  while (lo < hi) {
    const unsigned mid = (lo + hi) >> 1;
    int cnt = 0;
    #pragma unroll
    for (int j = 0; j < NC; ++j)
      cnt += (int)__popcll(__ballot(dv[j] <= mid));
    if (cnt >= KNN) hi = mid; else lo = mid + 1;
  }
  return hi;
}

__global__ __launch_bounds__(512, 4) void k_knn(
    const float* __restrict__ coords, const float* __restrict__ feat,
    float* __restrict__ agg)
{
  __shared__ float4 cs[VV];            // 64 KB: event coords (AoS)
  __shared__ uint2 lists[8][CAP];      // 16 KB: per-wave compact lists

  const int t = threadIdx.x, lane = t & 63;
  const int wv = __builtin_amdgcn_readfirstlane(t) >> 6;  // wave id, SGPR
  // XCD-aware swizzle (bijective: 512 = 8 * 64): all blocks on XCD x work
  // event x -> per-XCD L2 working set = 1 event (~1.5 MB) << 4 MB.
  const int bid0 = blockIdx.x;
  const int bid = (bid0 & 7) * 64 + (bid0 >> 3);
  const int ev = bid >> 6;             // 64 blocks per event
  const int qbase = (bid & 63) * 64;   // 64 queries per block
  const int evbase = ev * VV;

  {
    const float4* cg = (const float4*)coords + evbase;
    for (int i = t; i < VV; i += 512) cs[i] = cg[i];
  }
  __syncthreads();

  uint2* list = lists[wv];
  const float* fe = feat + (size_t)evbase * 64;
  const unsigned long long lmask = (1ull << lane) - 1ull;

  // Radius scan + stream compaction into the per-wave LDS list.
  auto scan = [&](unsigned rbits, int q, float4 qc) -> int {
    int M = 0;
    #pragma unroll 4
    for (int base = 0; base < VV; base += 64) {
      const int c = base + lane;
      const float4 cc = cs[c];
      const float dx = qc.x - cc.x, dy = qc.y - cc.y;
      const float dz = qc.z - cc.z, dw = qc.w - cc.w;
      const float dsq = dx * dx + dy * dy + dz * dz + dw * dw;
      const bool pred = (__float_as_uint(dsq) <= rbits) && (c != q);
      const unsigned long long bm = __ballot(pred);
      if (pred) {
        const int pos = M + (int)__popcll(bm & lmask);
        if (pos < CAP)
          list[pos] = make_uint2(__float_as_uint(dsq), (unsigned)c);
      }
      M += (int)__popcll(bm);
    }
    return M;
  };

  for (int qi = 0; qi < 8; ++qi) {
    const int q = qbase + wv * 8 + qi;   // local vertex id in event (SGPR)
    const float4 qc = cs[q];

    int M = scan(ONEB, q, qc);
    bool ok = true;

    if (M > CAP) {
      // Refine (rare, ~2.5% central queries): tau_sub = 40th smallest of the
      // 256 STORED entries (a fixed index-subsample => tau_sub >= true tau).
      // Re-scan at radius tau_sub: new count ~ 40*M/256 << CAP, and the set
      // {dsq <= tau_sub} provably contains the true 40 nearest.
      const unsigned t0 = bs40<4>(list, CAP, lane);
      M = scan(t0, q, qc);
      ok = (M <= CAP);
    }

    float vmax = -__builtin_inff(), vsum = 0.f;
    int selfcnt = 0;

    if (ok) {
      int Msel = M;
      if (M > KNN) {
        unsigned taub;
        if      (M <=  64) taub = bs40<1>(list, M, lane);
        else if (M <= 128) taub = bs40<2>(list, M, lane);
        else               taub = bs40<4>(list, M, lane);
        // Re-compact in place: keep entries with bits <= taub (~exactly 40).
        int S = 0;
        for (int be = 0; be < M; be += 64) {
          const int e = be + lane;
          uint2 en = make_uint2(0u, 0u);
          bool p = false;
          if (e < M) { en = list[e]; p = (en.x <= taub); }
          const unsigned long long bm = __ballot(p);
          if (p) list[S + (int)__popcll(bm & lmask)] = en;
          S += (int)__popcll(bm);
        }
        Msel = S;
      } else {
        selfcnt = KNN - M;   // out-of-radius slots -> self, w = 1
      }
      // Aggregate (lane = feature dim). Neighbor idx is wave-uniform ->
      // scalarize so the load is s[base] + lane*4 (no vector addr math).
      #pragma unroll 4
      for (int e = 0; e < Msel; ++e) {
        const uint2 en = list[e];                 // uniform broadcast read
        const int ei = __builtin_amdgcn_readfirstlane((int)en.y);
        const float w = __expf(-10.f * __uint_as_float(en.x));
        const float v = fe[(size_t)ei * 64 + lane] * w;
        vmax = fmaxf(vmax, v);
        vsum += v;
      }
    } else {
      // Exact full fallback (statistically unreachable)
      unsigned lo = 0, hi = ONEB;
      while (lo < hi) {
        const unsigned mid = (lo + hi) >> 1;
        const float fm = __uint_as_float(mid);
        int cnt = 0;
        for (int base = 0; base < VV; base += 64) {
          const int c = base + lane;
          const float4 cc = cs[c];
          const float dx = qc.x - cc.x, dy = qc.y - cc.y;
          const float dz = qc.z - cc.z, dw = qc.w - cc.w;
          const float dsq = dx * dx + dy * dy + dz * dz + dw * dw;
          cnt += (int)__popcll(__ballot(dsq <= fm && c != q));
        }
        if (cnt >= KNN) hi = mid; else lo = mid + 1;
      }
      const float tau = __uint_as_float(hi);
      for (int c = 0; c < VV; ++c) {
        if (c == q) continue;
        const float4 cc = cs[c];
        const float dx = qc.x - cc.x, dy = qc.y - cc.y;
        const float dz = qc.z - cc.z, dw = qc.w - cc.w;
        const float dsq = dx * dx + dy * dy + dz * dz + dw * dw;
        if (dsq <= tau) {
          const float w = __expf(-10.f * dsq);
          const float v = fe[(size_t)c * 64 + lane] * w;
          vmax = fmaxf(vmax, v);
          vsum += v;
        }
      }
    }

    const float fs = fe[(size_t)q * 64 + lane];
    if (selfcnt > 0) {
      vmax = fmaxf(vmax, fs);
      vsum += (float)selfcnt * fs;
    }

    const int g = evbase + q;
    agg[(size_t)g * 128 + lane]      = vmax;
    agg[(size_t)g * 128 + 64 + lane] = vsum * (1.f / 40.f);
  }
}

// ---------------------------------------------------------------------------
// Kernel 3: out = tanh(agg @ W_out[0:128,:] + xW + b_out), in place on d_out
// ---------------------------------------------------------------------------
__global__ __launch_bounds__(256) void k_out(
    const float* __restrict__ agg, const float* __restrict__ W_out,
    const float* __restrict__ b_out, float* __restrict__ out)
{
  __shared__ float at[64][128];  // reads are broadcast -> no pad; 16B aligned
  const int t = threadIdx.x;
  const int row0 = blockIdx.x * 64;

  #pragma unroll
  for (int i = 0; i < 32; ++i) {
    int idx = t + i * 256;
    at[idx >> 7][idx & 127] = agg[(size_t)row0 * 128 + idx];
  }
  __syncthreads();

  const int col = t & 127, who = t >> 7;
  #pragma unroll
  for (int p = 0; p < 2; ++p) {
    const int rb = who * 16 + p * 32;
    float acc[16];
    #pragma unroll
    for (int i = 0; i < 16; ++i) acc[i] = 0.f;
    for (int k = 0; k < 128; k += 4) {
      const float w0 = W_out[(size_t)(k + 0) * 128 + col];
      const float w1 = W_out[(size_t)(k + 1) * 128 + col];
      const float w2 = W_out[(size_t)(k + 2) * 128 + col];
      const float w3 = W_out[(size_t)(k + 3) * 128 + col];
      #pragma unroll
      for (int i = 0; i < 16; ++i) {
        const float4 a4 = *(const float4*)&at[rb + i][k];
        acc[i] += a4.x * w0 + a4.y * w1 + a4.z * w2 + a4.w * w3;
      }
    }
    const float bb = b_out[col];
    #pragma unroll
    for (int i = 0; i < 16; ++i) {
      const size_t o = (size_t)(row0 + rb + i) * 128 + col;
      float v = acc[i] + bb + out[o];   // out currently holds xW
      v = fminf(15.f, fmaxf(-15.f, v)); // tanh(|15|) == 1 in fp32
      const float e = __expf(2.f * v);
      out[o] = (e - 1.f) / (e + 1.f);
    }
  }
}

// ---------------------------------------------------------------------------
extern "C" void kernel_launch(void* const* d_in, const int* in_sizes, int n_in,
                              void* d_out, int out_size, void* d_ws, size_t ws_size,
                              hipStream_t stream) {
  const float* x      = (const float*)d_in[0];
  const float* W_prop = (const float*)d_in[1];
  const float* b_prop = (const float*)d_in[2];
  const float* W_sp   = (const float*)d_in[3];
  const float* b_sp   = (const float*)d_in[4];
  const float* W_out  = (const float*)d_in[5];
  const float* b_out  = (const float*)d_in[6];
  // d_in[7] = row_splits (regular, constants hard-coded)

  float* out = (float*)d_out;
  char* ws = (char*)d_ws;
  float* coords = (float*)ws;                                  // 512 KB
  float* feat   = (float*)(ws + (512 << 10));                  // 8 MB
  float* agg    = (float*)(ws + (512 << 10) + (8 << 20));      // 16 MB
  // total ws use: ~24.5 MB

  k_prep<<<NTOT / 64, 256, 0, stream>>>(x, W_prop, b_prop, W_sp, b_sp, W_out,
                                        coords, feat, out /* xW staged here */);
  k_knn<<<NB * (VV / 64), 512, 0, stream>>>(coords, feat, agg);
  k_out<<<NTOT / 64, 256, 0, stream>>>(agg, W_out, b_out, out);
}

// Round 7
// 206.151 us; speedup vs baseline: 2.7965x; 1.1348x over previous
//
#include <hip/hip_runtime.h>
#include <cstdint>
#include <cstddef>

// Problem constants (fixed by the reference file)
#define NB   8
#define VV   4096
#define KNN  40
#define NTOT 32768
#define CAP  256   // compact within-radius list capacity per query
#define INFB 0x7F800000u
#define ONEB 0x3F800000u

// ---------------------------------------------------------------------------
// Kernel 1: coords = x@W_sp + b_sp ; feat = x@W_prop + b_prop ;
//           xW = x @ W_out[128:192,:]  (written into d_out, fused later)
// ---------------------------------------------------------------------------
__global__ __launch_bounds__(256) void k_prep(
    const float* __restrict__ x, const float* __restrict__ W_prop,
    const float* __restrict__ b_prop, const float* __restrict__ W_sp,
    const float* __restrict__ b_sp, const float* __restrict__ W_out,
    float* __restrict__ coords, float* __restrict__ feat,
    float* __restrict__ xW)
{
  __shared__ float xt[64][64];   // reads are broadcast -> no pad needed
  const int t = threadIdx.x;
  const int row0 = blockIdx.x * 64;

  #pragma unroll
  for (int i = 0; i < 16; ++i) {
    int idx = t + i * 256;
    xt[idx >> 6][idx & 63] = x[(size_t)row0 * 64 + idx];
  }
  __syncthreads();

  // feat: 64 cols, 4 row-groups of 16
  {
    const int col = t & 63, rb = (t >> 6) * 16;
    float acc[16];
    #pragma unroll
    for (int i = 0; i < 16; ++i) acc[i] = b_prop[col];
    for (int k = 0; k < 64; k += 4) {
      const float w0 = W_prop[(k + 0) * 64 + col];
      const float w1 = W_prop[(k + 1) * 64 + col];
      const float w2 = W_prop[(k + 2) * 64 + col];
      const float w3 = W_prop[(k + 3) * 64 + col];
      #pragma unroll
      for (int i = 0; i < 16; ++i) {
        const float4 a4 = *(const float4*)&xt[rb + i][k];
        acc[i] += a4.x * w0 + a4.y * w1 + a4.z * w2 + a4.w * w3;
      }
    }
    #pragma unroll
    for (int i = 0; i < 16; ++i)
      feat[(size_t)(row0 + rb + i) * 64 + col] = acc[i];
  }

  // xW = x @ W_out[128:192,:]  (no bias here; b_out added in k_out)
  {
    const int col = t & 127, who = t >> 7;
    #pragma unroll
    for (int p = 0; p < 2; ++p) {
      const int rb = who * 16 + p * 32;
      float acc[16];
      #pragma unroll
      for (int i = 0; i < 16; ++i) acc[i] = 0.f;
      for (int k = 0; k < 64; k += 4) {
        const float w0 = W_out[(size_t)(128 + k + 0) * 128 + col];
        const float w1 = W_out[(size_t)(128 + k + 1) * 128 + col];
        const float w2 = W_out[(size_t)(128 + k + 2) * 128 + col];
        const float w3 = W_out[(size_t)(128 + k + 3) * 128 + col];
        #pragma unroll
        for (int i = 0; i < 16; ++i) {
          const float4 a4 = *(const float4*)&xt[rb + i][k];
          acc[i] += a4.x * w0 + a4.y * w1 + a4.z * w2 + a4.w * w3;
        }
      }
      #pragma unroll
      for (int i = 0; i < 16; ++i)
        xW[(size_t)(row0 + rb + i) * 128 + col] = acc[i];
    }
  }

  // coords: one row per thread (t<64)
  if (t < 64) {
    float a0 = b_sp[0], a1 = b_sp[1], a2 = b_sp[2], a3 = b_sp[3];
    for (int k = 0; k < 64; ++k) {
      const float xv = xt[t][k];
      a0 += xv * W_sp[k * 4 + 0];
      a1 += xv * W_sp[k * 4 + 1];
      a2 += xv * W_sp[k * 4 + 2];
      a3 += xv * W_sp[k * 4 + 3];
    }
    ((float4*)coords)[row0 + t] = make_float4(a0, a1, a2, a3);
  }
}

// ---------------------------------------------------------------------------
// Kernel 2: per-query KNN + weighted max/mean aggregation.
// 512 threads (8 waves) per block, 8 queries per wave, 2 blocks/CU resident
// (80 KB LDS) -> 4 waves/SIMD.
// ---------------------------------------------------------------------------
template <int NC>
__device__ __forceinline__ unsigned bs40(const uint2* __restrict__ list,
                                         int M, int lane) {
  // smallest bit pattern 'hi' with count(dsq_bits <= hi) >= KNN
  unsigned dv[NC];
  #pragma unroll
  for (int j = 0; j < NC; ++j) {
    const int e = lane + j * 64;
    dv[j] = (e < M) ? list[e].x : INFB;
  }
  unsigned lo = 0, hi = ONEB;
  while (lo < hi) {
    const unsigned mid = (lo + hi) >> 1;
    int cnt = 0;
    #pragma unroll
    for (int j = 0; j < NC; ++j)
      cnt += (int)__popcll(__ballot(dv[j] <= mid));
    if (cnt >= KNN) hi = mid; else lo = mid + 1;
  }
  return hi;
}

// One aggregation chunk: issue all N entry-reads + feature loads before the
// math consumes them (deep VMEM pipeline). N is compile-time -> all register
// arrays statically indexed.
#define AGG_CHUNK(J0, N)                                                     \
  {                                                                          \
    float fv[N], wgt[N];                                                     \
    _Pragma("unroll")                                                        \
    for (int j = 0; j < N; ++j) {                                            \
      const uint2 en = list[(J0) + j];        /* uniform ds_read_b64 */      \
      wgt[j] = __expf(-10.f * __uint_as_float(en.x));                        \
      const int ei = __builtin_amdgcn_readfirstlane((int)en.y);              \
      fv[j] = fe[(size_t)ei * 64 + lane];     /* coalesced 256B segment */   \
    }                                                                        \
    _Pragma("unroll")                                                        \
    for (int j = 0; j < N; ++j) {                                            \
      const float v = fv[j] * wgt[j];                                        \
      vmax = fmaxf(vmax, v);                                                 \
      vsum += v;                                                             \
    }                                                                        \
  }

__global__ __launch_bounds__(512, 4) void k_knn(
    const float* __restrict__ coords, const float* __restrict__ feat,
    float* __restrict__ agg)
{
  __shared__ float4 cs[VV];            // 64 KB: event coords (AoS)
  __shared__ uint2 lists[8][CAP];      // 16 KB: per-wave compact lists

  const int t = threadIdx.x, lane = t & 63;
  const int wvid = __builtin_amdgcn_readfirstlane(t) >> 6;  // wave id, SGPR
  // XCD-aware swizzle (bijective: 512 = 8 * 64): all blocks on XCD x work
  // event x -> per-XCD L2 working set = 1 event (~1.5 MB) << 4 MB.
  const int bid0 = blockIdx.x;
  const int bid = (bid0 & 7) * 64 + (bid0 >> 3);
  const int ev = bid >> 6;             // 64 blocks per event
  const int qbase = (bid & 63) * 64;   // 64 queries per block
  const int evbase = ev * VV;

  {
    const float4* cg = (const float4*)coords + evbase;
    for (int i = t; i < VV; i += 512) cs[i] = cg[i];
  }
  __syncthreads();

  uint2* list = lists[wvid];
  const float* fe = feat + (size_t)evbase * 64;
  const unsigned long long lmask = (1ull << lane) - 1ull;

  // Radius scan + stream compaction into the per-wave LDS list.
  auto scan = [&](unsigned rbits, int q, float4 qc) -> int {
    int M = 0;
    #pragma unroll 4
    for (int base = 0; base < VV; base += 64) {
      const int c = base + lane;
      const float4 cc = cs[c];
      const float dx = qc.x - cc.x, dy = qc.y - cc.y;
      const float dz = qc.z - cc.z, dw = qc.w - cc.w;
      const float dsq = dx * dx + dy * dy + dz * dz + dw * dw;
      const bool pred = (__float_as_uint(dsq) <= rbits) && (c != q);
      const unsigned long long bm = __ballot(pred);
      if (pred) {
        const int pos = M + (int)__popcll(bm & lmask);
        if (pos < CAP)
          list[pos] = make_uint2(__float_as_uint(dsq), (unsigned)c);
      }
      M += (int)__popcll(bm);
    }
    return M;
  };

  for (int qi = 0; qi < 8; ++qi) {
    const int q = qbase + wvid * 8 + qi;   // local vertex id in event (SGPR)
    const float4 qc = cs[q];

    int M = scan(ONEB, q, qc);
    bool ok = true;

    if (M > CAP) {
      // Refine (rare central queries): tau_sub = 40th smallest of the 256
      // STORED entries (fixed index-subsample => tau_sub >= true tau).
      // Re-scan at tau_sub: new count ~ 40*M/256 << CAP and provably
      // contains the true 40 nearest.
      const unsigned t0 = bs40<4>(list, CAP, lane);
      M = scan(t0, q, qc);
      ok = (M <= CAP);
    }

    float vmax = -__builtin_inff(), vsum = 0.f;

    if (ok) {
      int Msel;
      if (M > KNN) {
        unsigned taub;
        if      (M <=  64) taub = bs40<1>(list, M, lane);
        else if (M <= 128) taub = bs40<2>(list, M, lane);
        else               taub = bs40<4>(list, M, lane);
        // Re-compact in place: keep entries with bits <= taub (exactly 40
        // absent bit-ties, which are measure-zero for random data).
        int S = 0;
        for (int be = 0; be < M; be += 64) {
          const int e = be + lane;
          uint2 en = make_uint2(0u, 0u);
          bool p = false;
          if (e < M) { en = list[e]; p = (en.x <= taub); }
          const unsigned long long bm = __ballot(p);
          if (p) list[S + (int)__popcll(bm & lmask)] = en;
          S += (int)__popcll(bm);
        }
        Msel = S;
      } else {
        // Pad to exactly KNN with self entries. Reference: out-of-radius
        // slots -> self, dsq recomputed from replaced idx = 0 -> w = 1.
        if (lane >= M && lane < KNN)
          list[lane] = make_uint2(0u, (unsigned)q);
        Msel = KNN;
      }

      if (Msel == KNN) {
        // Fast path (virtually always): exactly 40 entries, fully unrolled
        // 16/16/8 chunks with loads issued ahead of consumption.
        AGG_CHUNK(0, 16)
        AGG_CHUNK(16, 16)
        AGG_CHUNK(32, 8)
      } else {
        // Tie case (Msel > 40): dynamic loop.
        #pragma unroll 4
        for (int e = 0; e < Msel; ++e) {
          const uint2 en = list[e];
          const int ei = __builtin_amdgcn_readfirstlane((int)en.y);
          const float w = __expf(-10.f * __uint_as_float(en.x));
          const float v = fe[(size_t)ei * 64 + lane] * w;
          vmax = fmaxf(vmax, v);
          vsum += v;
        }
      }
    } else {
      // Exact full fallback (statistically unreachable)
      unsigned lo = 0, hi = ONEB;
      while (lo < hi) {
        const unsigned mid = (lo + hi) >> 1;
        const float fm = __uint_as_float(mid);
        int cnt = 0;
        for (int base = 0; base < VV; base += 64) {
          const int c = base + lane;
          const float4 cc = cs[c];
          const float dx = qc.x - cc.x, dy = qc.y - cc.y;
          const float dz = qc.z - cc.z, dw = qc.w - cc.w;
          const float dsq = dx * dx + dy * dy + dz * dz + dw * dw;
          cnt += (int)__popcll(__ballot(dsq <= fm && c != q));
        }
        if (cnt >= KNN) hi = mid; else lo = mid + 1;
      }
      const float tau = __uint_as_float(hi);
      for (int c = 0; c < VV; ++c) {
        if (c == q) continue;
        const float4 cc = cs[c];
        const float dx = qc.x - cc.x, dy = qc.y - cc.y;
        const float dz = qc.z - cc.z, dw = qc.w - cc.w;
        const float dsq = dx * dx + dy * dy + dz * dz + dw * dw;
        if (dsq <= tau) {
          const float w = __expf(-10.f * dsq);
          const float v = fe[(size_t)c * 64 + lane] * w;
          vmax = fmaxf(vmax, v);
          vsum += v;
        }
      }
    }

    const int g = evbase + q;
    agg[(size_t)g * 128 + lane]      = vmax;
    agg[(size_t)g * 128 + 64 + lane] = vsum * (1.f / 40.f);
  }
}

// ---------------------------------------------------------------------------
// Kernel 3: out = tanh(agg @ W_out[0:128,:] + xW + b_out), in place on d_out
// ---------------------------------------------------------------------------
__global__ __launch_bounds__(256) void k_out(
    const float* __restrict__ agg, const float* __restrict__ W_out,
    const float* __restrict__ b_out, float* __restrict__ out)
{
  __shared__ float at[64][128];  // reads are broadcast -> no pad; 16B aligned
  const int t = threadIdx.x;
  const int row0 = blockIdx.x * 64;

  #pragma unroll
  for (int i = 0; i < 32; ++i) {
    int idx = t + i * 256;
    at[idx >> 7][idx & 127] = agg[(size_t)row0 * 128 + idx];
  }
  __syncthreads();

  const int col = t & 127, who = t >> 7;
  #pragma unroll
  for (int p = 0; p < 2; ++p) {
    const int rb = who * 16 + p * 32;
    float acc[16];
    #pragma unroll
    for (int i = 0; i < 16; ++i) acc[i] = 0.f;
    for (int k = 0; k < 128; k += 4) {
      const float w0 = W_out[(size_t)(k + 0) * 128 + col];
      const float w1 = W_out[(size_t)(k + 1) * 128 + col];
      const float w2 = W_out[(size_t)(k + 2) * 128 + col];
      const float w3 = W_out[(size_t)(k + 3) * 128 + col];
      #pragma unroll
      for (int i = 0; i < 16; ++i) {
        const float4 a4 = *(const float4*)&at[rb + i][k];
        acc[i] += a4.x * w0 + a4.y * w1 + a4.z * w2 + a4.w * w3;
      }
    }
    const float bb = b_out[col];
    #pragma unroll
    for (int i = 0; i < 16; ++i) {
      const size_t o = (size_t)(row0 + rb + i) * 128 + col;
      float v = acc[i] + bb + out[o];   // out currently holds xW
      v = fminf(15.f, fmaxf(-15.f, v)); // tanh(|15|) == 1 in fp32
      const float e = __expf(2.f * v);
      out[o] = (e - 1.f) / (e + 1.f);
    }
  }
}

// ---------------------------------------------------------------------------
extern "C" void kernel_launch(void* const* d_in, const int* in_sizes, int n_in,
                              void* d_out, int out_size, void* d_ws, size_t ws_size,
                              hipStream_t stream) {
  const float* x      = (const float*)d_in[0];
  const float* W_prop = (const float*)d_in[1];
  const float* b_prop = (const float*)d_in[2];
  const float* W_sp   = (const float*)d_in[3];
  const float* b_sp   = (const float*)d_in[4];
  const float* W_out  = (const float*)d_in[5];
  const float* b_out  = (const float*)d_in[6];
  // d_in[7] = row_splits (regular, constants hard-coded)

  float* out = (float*)d_out;
  char* ws = (char*)d_ws;
  float* coords = (float*)ws;                                  // 512 KB
  float* feat   = (float*)(ws + (512 << 10));                  // 8 MB
  float* agg    = (float*)(ws + (512 << 10) + (8 << 20));      // 16 MB
  // total ws use: ~24.5 MB

  k_prep<<<NTOT / 64, 256, 0, stream>>>(x, W_prop, b_prop, W_sp, b_sp, W_out,
                                        coords, feat, out /* xW staged here */);
  k_knn<<<NB * (VV / 64), 512, 0, stream>>>(coords, feat, agg);
  k_out<<<NTOT / 64, 256, 0, stream>>>(agg, W_out, b_out, out);
}